// Round 3
// baseline (3189.502 us; speedup 1.0000x reference)
//
#include <hip/hip_runtime.h>

#define HW 16384
#define W_IMG 128
#define CH 192
#define CIN 64
#define P_TOT 131072   // 8*16384
#define EPS 1e-5f

// ---------------------------------------------------------------- block reduce
__device__ __forceinline__ void blockReduce2(float& a, float& b2, float* lds) {
#pragma unroll
  for (int off = 32; off > 0; off >>= 1) {
    a  += __shfl_down(a,  off, 64);
    b2 += __shfl_down(b2, off, 64);
  }
  int wv = threadIdx.x >> 6, ln = threadIdx.x & 63;
  if (ln == 0) { lds[wv] = a; lds[4 + wv] = b2; }
  __syncthreads();
  if (threadIdx.x == 0) {
    a  = lds[0] + lds[1] + lds[2] + lds[3];
    b2 = lds[4] + lds[5] + lds[6] + lds[7];
  }
}

// ---------------------------------------------------------------- k0: transpose w_gates -> wT[c][row]
__global__ __launch_bounds__(256) void k0_prep(
    const float* __restrict__ w_g, float* __restrict__ wT)
{
  int idx = blockIdx.x * 256 + threadIdx.x;   // < 147456
  if (idx < 147456) {
    int row = idx / 192, c = idx - row * 192;
    wT[(size_t)c * 768 + row] = w_g[idx];
  }
}

// ---------------------------------------------------------------- k3: fused in_proj+LN+window attention
// one block per 4x4 window; writes amap (pre-GN, f32) into outp hnext region
__global__ __launch_bounds__(256) void k3_fused(
    const float* __restrict__ x,  const float* __restrict__ h,
    const float* __restrict__ w_in, const float* __restrict__ b_in,
    const float* __restrict__ ln_g, const float* __restrict__ ln_b,
    const float* __restrict__ w_qkv, const float* __restrict__ b_qkv,
    const float* __restrict__ w_proj, const float* __restrict__ b_proj,
    float* __restrict__ amap)
{
  __shared__ float buf[576 * 16];    // 36 KB; first 4096 floats double as comb[c][t]
  __shared__ float xnb[192 * 16];    // 12 KB
  __shared__ float sc[4 * 16 * 16];  //  4 KB
  __shared__ float mu_s[16], rs_s[16];
  const int tid = threadIdx.x;
  const int wid = blockIdx.x;
  const int b  = wid >> 10;
  const int wy = (wid >> 5) & 31;
  const int wx = wid & 31;
  const int pix0 = (wy * 4) * W_IMG + wx * 4;

  // stage A: load x(64ch) + h(192ch) 4x4 tile into comb[c][t] (t = ty*4+tx)
  for (int idx = tid; idx < 1024; idx += 256) {
    int cch = idx >> 2, ty = idx & 3;
    const float* src = (cch < 64)
        ? x + (size_t)(b * CIN + cch) * HW + pix0 + ty * W_IMG
        : h + (size_t)(b * CH + (cch - 64)) * HW + pix0 + ty * W_IMG;
    const float4 v = *(const float4*)src;
    float* d = &buf[cch * 16 + ty * 4];
    d[0] = v.x; d[1] = v.y; d[2] = v.z; d[3] = v.w;
  }
  __syncthreads();

  // stage B: in_proj  xnb[j][t] = b_in[j] + sum_c w_in[j][c]*comb[c][t]
  if (tid < 192) {
    const int j = tid;
    float acc[16];
    float bj = b_in[j];
#pragma unroll
    for (int t = 0; t < 16; ++t) acc[t] = bj;
    const float* wr = w_in + (size_t)j * 256;
#pragma unroll 4
    for (int c = 0; c < 256; ++c) {
      float wv = wr[c];
      const float* xr = &buf[c * 16];
#pragma unroll
      for (int t = 0; t < 16; ++t) acc[t] = fmaf(wv, xr[t], acc[t]);
    }
    float* o = &xnb[j * 16];
#pragma unroll
    for (int t = 0; t < 16; ++t) o[t] = acc[t];
  }
  __syncthreads();

  // stage C: LN stats per token
  if (tid < 16) {
    float s = 0.f, s2 = 0.f;
    for (int j = 0; j < 192; ++j) { float v = xnb[j * 16 + tid]; s += v; s2 += v * v; }
    float mu = s * (1.f / 192.f);
    float var = s2 * (1.f / 192.f) - mu * mu;
    mu_s[tid] = mu;
    rs_s[tid] = rsqrtf(fmaxf(var, 0.f) + EPS);
  }
  __syncthreads();

  // stage D: normalize in place
  for (int idx = tid; idx < 3072; idx += 256) {
    int j = idx >> 4, t = idx & 15;
    xnb[idx] = (xnb[idx] - mu_s[t]) * rs_s[t] * ln_g[j] + ln_b[j];
  }
  __syncthreads();

  // stage E: qkv[j][t] = b_qkv[j] + sum_c w_qkv[j][c]*xn[c][t]  (into buf, comb dead)
  for (int j = tid; j < 576; j += 256) {
    float acc[16];
    float bj = b_qkv[j];
#pragma unroll
    for (int t = 0; t < 16; ++t) acc[t] = bj;
    const float* wr = w_qkv + (size_t)j * 192;
#pragma unroll 4
    for (int c = 0; c < 192; ++c) {
      float wv = wr[c];
      const float* xr = &xnb[c * 16];
#pragma unroll
      for (int t = 0; t < 16; ++t) acc[t] = fmaf(wv, xr[t], acc[t]);
    }
    float* qr = &buf[j * 16];
#pragma unroll
    for (int t = 0; t < 16; ++t) qr[t] = acc[t];
  }
  __syncthreads();

  // stage F: scores  sc[h][t1][t2]
  const float scale = 0.14433756729740643f;  // 48^-0.5
  for (int q = tid; q < 1024; q += 256) {
    int hh = q >> 8, t1 = (q >> 4) & 15, t2 = q & 15;
    const float* qq = &buf[(hh * 48) * 16 + t1];
    const float* kk = &buf[(192 + hh * 48) * 16 + t2];
    float sv = 0.f;
#pragma unroll
    for (int d = 0; d < 48; ++d) sv = fmaf(qq[d * 16], kk[d * 16], sv);
    sc[q] = sv * scale;
  }
  __syncthreads();

  // stage G: softmax over t2
  if (tid < 64) {
    float* row = &sc[tid * 16];
    float m = row[0];
#pragma unroll
    for (int t = 1; t < 16; ++t) m = fmaxf(m, row[t]);
    float sum = 0.f;
#pragma unroll
    for (int t = 0; t < 16; ++t) { float e = __expf(row[t] - m); row[t] = e; sum += e; }
    float inv = 1.f / sum;
#pragma unroll
    for (int t = 0; t < 16; ++t) row[t] *= inv;
  }
  __syncthreads();

  // stage H: attn-out[c][t] = sum_t2 P[h(c)][t][t2]*v[t2][c]  (into xnb)
  for (int rnd = 0; rnd < 12; ++rnd) {
    int q = rnd * 256 + tid;  // < 3072
    int cc = q >> 4, t = q & 15;
    const float* pr = &sc[(cc / 48) * 256 + t * 16];
    const float* vr = &buf[(384 + cc) * 16];
    float sv = 0.f;
#pragma unroll
    for (int t2 = 0; t2 < 16; ++t2) sv = fmaf(pr[t2], vr[t2], sv);
    xnb[cc * 16 + t] = sv;
  }
  __syncthreads();

  // stage I: out proj -> amap (raw, pre-GN) f32 NCHW
  if (tid < 192) {
    const int o = tid;
    float acc[16];
    float bo = b_proj[o];
#pragma unroll
    for (int t = 0; t < 16; ++t) acc[t] = bo;
    const float* wr = w_proj + (size_t)o * 192;
#pragma unroll 4
    for (int c = 0; c < 192; ++c) {
      float wv = wr[c];
      const float* xr = &xnb[c * 16];
#pragma unroll
      for (int t = 0; t < 16; ++t) acc[t] = fmaf(wv, xr[t], acc[t]);
    }
    float* op = amap + (size_t)(b * CH + o) * HW + pix0;
#pragma unroll
    for (int ty = 0; ty < 4; ++ty) {
      *(float4*)(op + ty * W_IMG) =
          make_float4(acc[ty * 4], acc[ty * 4 + 1], acc[ty * 4 + 2], acc[ty * 4 + 3]);
    }
  }
}

// ---------------------------------------------------------------- k4: GN stats (sum, sum2) per (b, group)
__global__ __launch_bounds__(256) void k4_stats(
    const float* __restrict__ src, float* __restrict__ stats)
{
  __shared__ float lds[8];
  int blk = blockIdx.x;             // 24576 = 1536 bc * 16 chunks
  int chunk = blk & 15, bc = blk >> 4;
  int b = bc / 192, cch = bc % 192;
  const float4 v = *(const float4*)(src + (size_t)bc * HW + chunk * 1024 + threadIdx.x * 4);
  float s  = v.x + v.y + v.z + v.w;
  float s2 = v.x * v.x + v.y * v.y + v.z * v.z + v.w * v.w;
  blockReduce2(s, s2, lds);
  if (threadIdx.x == 0) {
    atomicAdd(&stats[(b * 8 + cch / 24) * 2],     s);
    atomicAdd(&stats[(b * 8 + cch / 24) * 2 + 1], s2);
  }
}

// ---------------------------------------------------------------- k4b: per-(b,c) GN scale/shift for amap
__global__ __launch_bounds__(256) void k4b_scale(
    const float* __restrict__ stats, const float* __restrict__ gn_g,
    const float* __restrict__ gn_b, float* __restrict__ scaleS, float* __restrict__ shiftS)
{
  int idx = blockIdx.x * 256 + threadIdx.x;
  if (idx >= 1536) return;
  int b = idx / 192, cch = idx % 192, g = cch / 24;
  float n = 24.f * HW;
  float mu  = stats[(b * 8 + g) * 2] / n;
  float var = stats[(b * 8 + g) * 2 + 1] / n - mu * mu;
  float rs = rsqrtf(fmaxf(var, 0.f) + EPS);
  float scl = rs * gn_g[cch];
  scaleS[idx] = scl;
  shiftS[idx] = gn_b[cch] - mu * scl;
}

// ---------------------------------------------------------------- k6: gates GEMM (+folded GN) + LSTM
// block: 64 pixels; amap tile (normalized) staged once in LDS; overwrites hnext in place
__global__ __launch_bounds__(256) void k6_gates(
    float* __restrict__ outp,            // hnext region == amap (in), hnext-pre (out)
    const float* __restrict__ wT,        // [c][row] 192x768
    const float* __restrict__ b_g, const float* __restrict__ cin,
    const float* __restrict__ scaleS, const float* __restrict__ shiftS)
{
  __shared__ float tile[192 * 64];   // 48 KB, [c][p] normalized amap
  const int tid = threadIdx.x;
  const int b  = blockIdx.x >> 8;            // 2048 blocks = 8 b x 256
  const int s0 = (blockIdx.x & 255) * 64;
  float* cout = outp + (size_t)P_TOT * CH;

  for (int idx = tid; idx < 12288; idx += 256) {
    int c = idx >> 6, p = idx & 63;
    float raw = outp[(size_t)(b * CH + c) * HW + s0 + p];
    tile[idx] = fmaf(raw, scaleS[b * CH + c], shiftS[b * CH + c]);
  }
  __syncthreads();

  const int lane = tid & 63;
  const int wv = __builtin_amdgcn_readfirstlane(tid >> 6);

  for (int jg = wv * 6; jg < wv * 6 + 6; ++jg) {
    const int j0 = jg * 8;
    float acc[32];
#pragma unroll
    for (int k = 0; k < 4; ++k)
#pragma unroll
      for (int r = 0; r < 8; ++r) acc[k * 8 + r] = b_g[k * 192 + j0 + r];
#pragma unroll 2
    for (int c = 0; c < 192; ++c) {
      float a = tile[c * 64 + lane];
      const float* wc = wT + (size_t)c * 768 + j0;
#pragma unroll
      for (int k = 0; k < 4; ++k)
#pragma unroll
        for (int r = 0; r < 8; ++r)
          acc[k * 8 + r] = fmaf(a, wc[k * 192 + r], acc[k * 8 + r]);
    }
#pragma unroll
    for (int r = 0; r < 8; ++r) {
      size_t base = (size_t)(b * CH + j0 + r) * HW + s0 + lane;
      float ci = acc[r], cf = acc[8 + r], co = acc[16 + r], cg = acc[24 + r];
      float iv = 1.f / (1.f + __expf(-ci));
      float fv = 1.f / (1.f + __expf(-cf));
      float ov = 1.f / (1.f + __expf(-co));
      float gv = 1.f - 2.f / (__expf(2.f * cg) + 1.f);
      float cn = fmaf(fv, cin[base], iv * gv);
      cout[base] = cn;                                   // cnext (final)
      float th = 1.f - 2.f / (__expf(2.f * cn) + 1.f);
      outp[base] = ov * th;                              // hnext pre-GN
    }
  }
}

// ---------------------------------------------------------------- k7: GN(hnext) in place
__global__ __launch_bounds__(256) void k7_hnext(
    const float* __restrict__ stats2,
    const float* __restrict__ gn_g, const float* __restrict__ gn_b,
    float* __restrict__ outp)
{
  int blk = blockIdx.x;
  int chunk = blk & 15, bc = blk >> 4;
  int b = bc / 192, cch = bc % 192, g = cch / 24;
  float n = 24.f * HW;
  float mu  = stats2[(b * 8 + g) * 2] / n;
  float var = stats2[(b * 8 + g) * 2 + 1] / n - mu * mu;
  float rs = rsqrtf(fmaxf(var, 0.f) + EPS);
  float scl = rs * gn_g[cch];
  float shf = gn_b[cch] - mu * scl;
  float* p = outp + (size_t)bc * HW + chunk * 1024 + threadIdx.x * 4;
  float4 v = *(float4*)p;
  v.x = fmaf(v.x, scl, shf); v.y = fmaf(v.y, scl, shf);
  v.z = fmaf(v.z, scl, shf); v.w = fmaf(v.w, scl, shf);
  *(float4*)p = v;
}

// ---------------------------------------------------------------- launch
extern "C" void kernel_launch(void* const* d_in, const int* in_sizes, int n_in,
                              void* d_out, int out_size, void* d_ws, size_t ws_size,
                              hipStream_t stream) {
  (void)in_sizes; (void)n_in; (void)out_size; (void)ws_size;
  const float* x      = (const float*)d_in[0];
  const float* h      = (const float*)d_in[1];
  const float* c      = (const float*)d_in[2];
  const float* w_in   = (const float*)d_in[3];
  const float* b_in   = (const float*)d_in[4];
  const float* ln_g   = (const float*)d_in[5];
  const float* ln_b   = (const float*)d_in[6];
  const float* w_qkv  = (const float*)d_in[7];
  const float* b_qkv  = (const float*)d_in[8];
  const float* w_proj = (const float*)d_in[9];
  const float* b_proj = (const float*)d_in[10];
  const float* gn_g   = (const float*)d_in[11];
  const float* gn_b   = (const float*)d_in[12];
  const float* w_g    = (const float*)d_in[13];
  const float* b_g    = (const float*)d_in[14];
  float* outp = (float*)d_out;
  char* ws = (char*)d_ws;
  // workspace: 603,136 B total
  float* wT     = (float*)ws;                   // 589,824 B
  float* statsA = (float*)(ws + 589824);        // 512 B
  float* stats2 = (float*)(ws + 590336);        // 512 B
  float* scaleS = (float*)(ws + 590848);        // 6,144 B
  float* shiftS = (float*)(ws + 596992);        // 6,144 B

  hipMemsetAsync(statsA, 0, 1024, stream);      // statsA + stats2

  k0_prep  <<<576, 256, 0, stream>>>(w_g, wT);
  k3_fused <<<8192, 256, 0, stream>>>(x, h, w_in, b_in, ln_g, ln_b,
                                      w_qkv, b_qkv, w_proj, b_proj, outp);
  k4_stats <<<24576, 256, 0, stream>>>(outp, statsA);
  k4b_scale<<<6, 256, 0, stream>>>(statsA, gn_g, gn_b, scaleS, shiftS);
  k6_gates <<<2048, 256, 0, stream>>>(outp, wT, b_g, c, scaleS, shiftS);
  k4_stats <<<24576, 256, 0, stream>>>(outp, stats2);
  k7_hnext <<<24576, 256, 0, stream>>>(stats2, gn_g, gn_b, outp);
}